// Round 1
// baseline (274.639 us; speedup 1.0000x reference)
//
#include <hip/hip_runtime.h>
#include <stdint.h>

// RBF kernel matrix: out[i][j] = exp(-GAMMA * ||x1_i - x2_j||^2)
//  = exp(-GAMMA * (n1[i] - 2*cross[i][j] + n2[j]))
// M=N=8192, K=128. Write-BW-bound: 268 MB output -> ~43 us floor @6.3 TB/s.
// cross via fp16 MFMA (error ~1e-4 on output, threshold 1.125e-2).

#define GAMMA_F 0.005f

typedef __attribute__((ext_vector_type(8))) _Float16 half8;
typedef __attribute__((ext_vector_type(2))) _Float16 half2v;
typedef __attribute__((ext_vector_type(4))) float floatx4;

__device__ __forceinline__ void async_copy16(const void* g, void* l) {
    __builtin_amdgcn_global_load_lds(
        (const __attribute__((address_space(1))) void*)g,
        (__attribute__((address_space(3))) void*)l,
        16, 0, 0);
}

// ---- prep: fp32 rows -> fp16 rows + fp32 row sum-of-squares ----
// 1 wave per row (64 lanes x float2), 4 rows per 256-thread block.
__global__ __launch_bounds__(256) void rbf_prep(
    const float* __restrict__ x1, const float* __restrict__ x2,
    _Float16* __restrict__ Ah, _Float16* __restrict__ Bh,
    float* __restrict__ n1, float* __restrict__ n2) {
    const int wave = threadIdx.x >> 6;
    const int lane = threadIdx.x & 63;
    const int row = blockIdx.x * 4 + wave;  // 0..16383
    const float* src; _Float16* dst; float* nrm; int r;
    if (row < 8192) { src = x1; dst = Ah; nrm = n1; r = row; }
    else            { src = x2; dst = Bh; nrm = n2; r = row - 8192; }
    const float2 v = ((const float2*)(src + (size_t)r * 128))[lane];
    float s = v.x * v.x + v.y * v.y;  // norms in full fp32
    half2v h;
    h.x = (_Float16)v.x;  // v_cvt_f16_f32 (RNE)
    h.y = (_Float16)v.y;
    ((half2v*)(dst + (size_t)r * 128))[lane] = h;
    #pragma unroll
    for (int off = 32; off > 0; off >>= 1) s += __shfl_down(s, off, 64);
    if (lane == 0) nrm[r] = s;
}

// ---- main: 128x128 tile / block, full K=128 staged once, fused exp epilogue ----
__global__ __launch_bounds__(256, 2) void rbf_main(
    const _Float16* __restrict__ A,   // [8192][128] fp16 (x1)
    const _Float16* __restrict__ B,   // [8192][128] fp16 (x2)
    const float* __restrict__ n1, const float* __restrict__ n2,
    float* __restrict__ out) {
    // 32 KB each; 64 KB total -> 2 blocks/CU
    __shared__ alignas(16) _Float16 As[128 * 128];
    __shared__ alignas(16) _Float16 Bs[128 * 128];

    const int t  = threadIdx.x;
    const int tm = blockIdx.x >> 6;
    const int tn = blockIdx.x & 63;

    // Each tile = 128 consecutive rows x full K -> contiguous 32 KB in global.
    const char* Ag = (const char*)(A + (size_t)tm * 128 * 128);
    const char* Bg = (const char*)(B + (size_t)tn * 128 * 128);
    char* AsB = (char*)As;
    char* BsB = (char*)Bs;

    // Stage with global_load_lds width=16. LDS side is forced to
    // base + lane*16, so the bank-conflict swizzle is applied on the
    // GLOBAL side: LDS chunk p=(m,c') holds global chunk (m, c'^(m&15)).
    // Wave still fetches a contiguous 1 KB global region -> coalesced.
    #pragma unroll
    for (int i = 0; i < 8; ++i) {
        const int p = i * 256 + t;          // LDS 16B-chunk index, 0..2047
        const int m = p >> 4;               // row in tile
        const int c = (p & 15) ^ (m & 15);  // swizzled source chunk in row
        const int goff = m * 256 + c * 16;  // row = 256 B = 16 chunks
        async_copy16(Ag + goff, AsB + p * 16);
        async_copy16(Bg + goff, BsB + p * 16);
    }
    __syncthreads();

    const int lane   = t & 63;
    const int wave   = t >> 6;
    const int ln     = lane & 15;
    const int q      = lane >> 4;
    const int wave_m = (wave & 1) * 64;
    const int wave_n = (wave >> 1) * 64;

    floatx4 acc[4][4] = {};  // 64 acc regs/lane

    // A-frag layout (16x16x32): A[m=ln][k=q*8+j]; B^T input has identical
    // addressing. Chunk index within row = 4*ks + q; apply read-side XOR.
    // Banks: ((4ks+q)^ln)*4 % 32 -> 2-way aliasing only (free, m136).
    #pragma unroll
    for (int ks = 0; ks < 4; ++ks) {
        const int xk = ((4 * ks + q) ^ ln) * 16;
        half8 a_frag[4], b_frag[4];
        #pragma unroll
        for (int i = 0; i < 4; ++i) {
            a_frag[i] = *(const half8*)(AsB + (wave_m + i * 16 + ln) * 256 + xk);
            b_frag[i] = *(const half8*)(BsB + (wave_n + i * 16 + ln) * 256 + xk);
        }
        #pragma unroll
        for (int i = 0; i < 4; ++i)
            #pragma unroll
            for (int j = 0; j < 4; ++j)
                acc[i][j] = __builtin_amdgcn_mfma_f32_16x16x32_f16(
                    a_frag[i], b_frag[j], acc[i][j], 0, 0, 0);
    }

    // Epilogue: C/D layout col=ln, row=q*4+reg (verified m89/m91, dtype-indep).
    const int row0 = tm * 128 + wave_m;
    const int col0 = tn * 128 + wave_n + ln;
    float n2v[4];
    #pragma unroll
    for (int j = 0; j < 4; ++j) n2v[j] = n2[col0 + j * 16];

    #pragma unroll
    for (int i = 0; i < 4; ++i) {
        const int r0 = row0 + i * 16 + q * 4;      // multiple of 4 -> float4 ok
        const float4 nv = *(const float4*)(n1 + r0);
        const float n1v[4] = {nv.x, nv.y, nv.z, nv.w};
        #pragma unroll
        for (int r = 0; r < 4; ++r) {
            float* orow = out + (size_t)(r0 + r) * 8192 + col0;
            #pragma unroll
            for (int j = 0; j < 4; ++j) {
                const float s = n1v[r] + n2v[j] - 2.0f * acc[i][j][r];
                orow[j * 16] = __expf(-GAMMA_F * s);
            }
        }
    }
}

extern "C" void kernel_launch(void* const* d_in, const int* in_sizes, int n_in,
                              void* d_out, int out_size, void* d_ws, size_t ws_size,
                              hipStream_t stream) {
    const float* x1 = (const float*)d_in[0];
    const float* x2 = (const float*)d_in[1];
    float* out = (float*)d_out;

    // ws layout: Ah fp16 2MB | Bh fp16 2MB | n1 32KB | n2 32KB  (4.07 MB total)
    char* ws = (char*)d_ws;
    _Float16* Ah = (_Float16*)ws;
    _Float16* Bh = (_Float16*)(ws + (size_t)2 * 1024 * 1024);
    float* n1 = (float*)(ws + (size_t)4 * 1024 * 1024);
    float* n2 = (float*)(ws + (size_t)4 * 1024 * 1024 + 32 * 1024);

    rbf_prep<<<4096, 256, 0, stream>>>(x1, x2, Ah, Bh, n1, n2);
    rbf_main<<<4096, 256, 0, stream>>>(Ah, Bh, n1, n2, out);
}

// Round 2
// 274.629 us; speedup vs baseline: 1.0000x; 1.0000x over previous
//
#include <hip/hip_runtime.h>
#include <stdint.h>

// RBF kernel matrix: out[i][j] = exp(-GAMMA * ||x1_i - x2_j||^2)
//  = exp2( -Cl*(n1[i]+n2[j]) + 2*Cl*cross[i][j] ),  Cl = GAMMA*log2(e)
// M=N=8192, K=128. Write-BW-bound: 268 MB output -> ~43 us floor @6.3 TB/s.
// cross via fp16 MFMA (absmax 3.9e-3 measured R1, threshold 1.125e-2).
//
// R2 change: MFMA operands SWAPPED (mfma(b,a)) so the accumulator's reg
// dimension lands on output COLUMNS -> each thread stores 16 aligned float4
// instead of 64 scalar dwords. Norms pre-scaled by -Cl in prep; epilogue is
// add + fma + v_exp_f32 per element.

#define CL_F     0.0072134752f   // GAMMA * log2(e),  GAMMA = 0.005
#define TWO_CL_F 0.0144269504f

typedef __attribute__((ext_vector_type(8))) _Float16 half8;
typedef __attribute__((ext_vector_type(2))) _Float16 half2v;
typedef __attribute__((ext_vector_type(4))) float floatx4;

__device__ __forceinline__ void async_copy16(const void* g, void* l) {
    __builtin_amdgcn_global_load_lds(
        (const __attribute__((address_space(1))) void*)g,
        (__attribute__((address_space(3))) void*)l,
        16, 0, 0);
}

// ---- prep: fp32 rows -> fp16 rows + (-Cl * row sum-of-squares) ----
// 1 wave per row (64 lanes x float2), 4 rows per 256-thread block.
__global__ __launch_bounds__(256) void rbf_prep(
    const float* __restrict__ x1, const float* __restrict__ x2,
    _Float16* __restrict__ Ah, _Float16* __restrict__ Bh,
    float* __restrict__ n1, float* __restrict__ n2) {
    const int wave = threadIdx.x >> 6;
    const int lane = threadIdx.x & 63;
    const int row = blockIdx.x * 4 + wave;  // 0..16383
    const float* src; _Float16* dst; float* nrm; int r;
    if (row < 8192) { src = x1; dst = Ah; nrm = n1; r = row; }
    else            { src = x2; dst = Bh; nrm = n2; r = row - 8192; }
    const float2 v = ((const float2*)(src + (size_t)r * 128))[lane];
    float s = v.x * v.x + v.y * v.y;  // norms in full fp32
    half2v h;
    h.x = (_Float16)v.x;  // v_cvt_f16_f32 (RNE)
    h.y = (_Float16)v.y;
    ((half2v*)(dst + (size_t)r * 128))[lane] = h;
    #pragma unroll
    for (int off = 32; off > 0; off >>= 1) s += __shfl_down(s, off, 64);
    if (lane == 0) nrm[r] = -CL_F * s;   // pre-scaled for exp2 epilogue
}

// ---- main: 128x128 tile / block, full K=128 staged once, fused exp2 epilogue ----
__global__ __launch_bounds__(256, 2) void rbf_main(
    const _Float16* __restrict__ A,   // [8192][128] fp16 (x1)
    const _Float16* __restrict__ B,   // [8192][128] fp16 (x2)
    const float* __restrict__ n1, const float* __restrict__ n2,  // pre-scaled -Cl*||.||^2
    float* __restrict__ out) {
    // 32 KB each; 64 KB total -> 2 blocks/CU
    __shared__ alignas(16) _Float16 As[128 * 128];
    __shared__ alignas(16) _Float16 Bs[128 * 128];

    const int t  = threadIdx.x;
    const int tm = blockIdx.x >> 6;
    const int tn = blockIdx.x & 63;

    // Each tile = 128 consecutive rows x full K -> contiguous 32 KB in global.
    const char* Ag = (const char*)(A + (size_t)tm * 128 * 128);
    const char* Bg = (const char*)(B + (size_t)tn * 128 * 128);
    char* AsB = (char*)As;
    char* BsB = (char*)Bs;

    // Stage with global_load_lds width=16. LDS side is forced to
    // base + lane*16, so the bank-conflict swizzle is applied on the
    // GLOBAL side: LDS chunk p=(m,c') holds global chunk (m, c'^(m&15)).
    // Wave still fetches a contiguous 1 KB global region -> coalesced.
    #pragma unroll
    for (int i = 0; i < 8; ++i) {
        const int p = i * 256 + t;          // LDS 16B-chunk index, 0..2047
        const int m = p >> 4;               // row in tile
        const int c = (p & 15) ^ (m & 15);  // swizzled source chunk in row
        const int goff = m * 256 + c * 16;  // row = 256 B = 16 chunks
        async_copy16(Ag + goff, AsB + p * 16);
        async_copy16(Bg + goff, BsB + p * 16);
    }
    __syncthreads();

    const int lane   = t & 63;
    const int wave   = t >> 6;
    const int ln     = lane & 15;
    const int q      = lane >> 4;
    const int wave_m = (wave & 1) * 64;
    const int wave_n = (wave >> 1) * 64;

    floatx4 acc[4][4] = {};  // 64 acc regs/lane

    // Frag layout (16x16x32 op): X[r=ln][k=q*8+j]. Chunk index within a row
    // = 4*ks + q; read-side XOR matches the staging swizzle.
    // Banks: ((4ks+q)^ln)*4 % 32 -> 2-way aliasing only (free, m136).
    #pragma unroll
    for (int ks = 0; ks < 4; ++ks) {
        const int xk = ((4 * ks + q) ^ ln) * 16;
        half8 a_frag[4], b_frag[4];
        #pragma unroll
        for (int i = 0; i < 4; ++i) {
            a_frag[i] = *(const half8*)(AsB + (wave_m + i * 16 + ln) * 256 + xk);
            b_frag[i] = *(const half8*)(BsB + (wave_n + i * 16 + ln) * 256 + xk);
        }
        // SWAPPED operands: D[m'][n'] = sum_k B[m',k]*A[n',k] = cross^T.
        // C/D layout (m91): col=ln -> n' = TRUE ROW (A's m);
        //                   row=q*4+reg -> m' = TRUE COL (B's n).
        // => each lane's 4 regs are 4 consecutive output columns: float4 store.
        #pragma unroll
        for (int i = 0; i < 4; ++i)
            #pragma unroll
            for (int j = 0; j < 4; ++j)
                acc[i][j] = __builtin_amdgcn_mfma_f32_16x16x32_f16(
                    b_frag[j], a_frag[i], acc[i][j], 0, 0, 0);
    }

    // Epilogue: lane (ln,q), acc[i][j] regs r=0..3 hold
    //   row = tm*128 + wave_m + i*16 + ln
    //   col = tn*128 + wave_n + j*16 + q*4 + r
    const int row0 = tm * 128 + wave_m + ln;       // + i*16
    const int colb = tn * 128 + wave_n + q * 4;    // + j*16

    float n1s[4];
    #pragma unroll
    for (int i = 0; i < 4; ++i) n1s[i] = n1[row0 + i * 16];  // gathered, L2-hit

    float4 n2s[4];
    #pragma unroll
    for (int j = 0; j < 4; ++j) n2s[j] = *(const float4*)(n2 + colb + j * 16);

    #pragma unroll
    for (int i = 0; i < 4; ++i) {
        float* orow = out + (size_t)(row0 + i * 16) * 8192 + colb;
        #pragma unroll
        for (int j = 0; j < 4; ++j) {
            float4 o;
            o.x = __builtin_amdgcn_exp2f(fmaf(acc[i][j][0], TWO_CL_F, n1s[i] + n2s[j].x));
            o.y = __builtin_amdgcn_exp2f(fmaf(acc[i][j][1], TWO_CL_F, n1s[i] + n2s[j].y));
            o.z = __builtin_amdgcn_exp2f(fmaf(acc[i][j][2], TWO_CL_F, n1s[i] + n2s[j].z));
            o.w = __builtin_amdgcn_exp2f(fmaf(acc[i][j][3], TWO_CL_F, n1s[i] + n2s[j].w));
            *(float4*)(orow + j * 16) = o;   // global_store_dwordx4
        }
    }
}

extern "C" void kernel_launch(void* const* d_in, const int* in_sizes, int n_in,
                              void* d_out, int out_size, void* d_ws, size_t ws_size,
                              hipStream_t stream) {
    const float* x1 = (const float*)d_in[0];
    const float* x2 = (const float*)d_in[1];
    float* out = (float*)d_out;

    // ws layout: Ah fp16 2MB | Bh fp16 2MB | n1 32KB | n2 32KB  (4.07 MB total)
    char* ws = (char*)d_ws;
    _Float16* Ah = (_Float16*)ws;
    _Float16* Bh = (_Float16*)(ws + (size_t)2 * 1024 * 1024);
    float* n1 = (float*)(ws + (size_t)4 * 1024 * 1024);
    float* n2 = (float*)(ws + (size_t)4 * 1024 * 1024 + 32 * 1024);

    rbf_prep<<<4096, 256, 0, stream>>>(x1, x2, Ah, Bh, n1, n2);
    rbf_main<<<4096, 256, 0, stream>>>(Ah, Bh, n1, n2, out);
}